// Round 2
// baseline (20.804 us; speedup 1.0000x reference)
//
#include <hip/hip_runtime.h>

#define PLACEHOLDER (-1)
#define T 1024
#define NW (T / 64)

__device__ __forceinline__ void comb(float& v, int& i, float v2, int i2) {
    // argmax combine, numpy tie-break: lower index wins on equal value
    if (v2 > v || (v2 == v && i2 < i)) { v = v2; i = i2; }
}

// block-wide argmax; returns winning index to ALL threads
__device__ int block_argmax(float bv, int bi, float* s_v, int* s_i) {
    #pragma unroll
    for (int off = 32; off > 0; off >>= 1) {
        float v2 = __shfl_down(bv, off);
        int   i2 = __shfl_down(bi, off);
        comb(bv, bi, v2, i2);
    }
    const int tid = threadIdx.x;
    if ((tid & 63) == 0) { s_v[tid >> 6] = bv; s_i[tid >> 6] = bi; }
    __syncthreads();
    if (tid == 0) {
        for (int w = 1; w < NW; ++w) comb(bv, bi, s_v[w], s_i[w]);
        s_i[0] = bi;
    }
    __syncthreads();
    int r = s_i[0];
    __syncthreads();   // s_v/s_i safely reusable after this
    return r;
}

__global__ __launch_bounds__(T) void fused_kernel(
    const float* __restrict__ dp, const float* __restrict__ tp,
    const float* __restrict__ up, const float* __restrict__ q,
    const int* __restrict__ cu, const int* __restrict__ did,
    const int* __restrict__ bonus, const void* __restrict__ grd,
    int* __restrict__ out, int B, int V, int S)
{
    const int b   = blockIdx.x;
    const int tid = threadIdx.x;

    __shared__ float s_v[NW];
    __shared__ int   s_i[NW];
    __shared__ int   s_flags[2];     // [0]: any byte>1  [1]: any nonzero byte at pos%4!=0
    __shared__ int   sh_tok, sh_acc;

    // ---- detect is_greedy encoding from its first B bytes (safe: never OOB) ----
    if (tid < 2) s_flags[tid] = 0;
    __syncthreads();
    const unsigned char* gb = (const unsigned char*)grd;
    if (tid < B) {
        unsigned char c = gb[tid];
        if (c > 1) s_flags[0] = 1;
        if ((tid & 3) && c) s_flags[1] = 1;
    }
    __syncthreads();
    bool g;
    if (s_flags[0])      g = (((const float*)grd)[b] != 0.0f);  // float32 bools
    else if (s_flags[1]) g = (gb[b] != 0);                      // 1-byte bools
    else                 g = (((const int*)grd)[b] != 0);       // int32 bools

    const int start = (b == 0) ? 0 : cu[b - 1];
    const int len   = cu[b] - start;
    int* row = out + b * (S + 1);

    const int V4 = V >> 2;
    bool allacc = true;
    int  p = 0;
    for (; p < len; ++p) {
        const int i = start + p;
        const float* __restrict__ trow = tp + (size_t)i * V;
        int tok, acc;
        if (g) {
            // greedy: token = argmax(target row); accept iff draft matches
            float bv = -1.0f; int bi = 0;
            const float4* t4 = (const float4*)trow;
            for (int j = tid; j < V4; j += T) {
                float4 t = t4[j]; const int base = j << 2;
                if (t.x > bv) { bv = t.x; bi = base;     }
                if (t.y > bv) { bv = t.y; bi = base + 1; }
                if (t.z > bv) { bv = t.z; bi = base + 2; }
                if (t.w > bv) { bv = t.w; bi = base + 3; }
            }
            for (int j = (V4 << 2) + tid; j < V; j += T) {
                float tv = trow[j];
                if (tv > bv) { bv = tv; bi = j; }
            }
            tok = block_argmax(bv, bi, s_v, s_i);
            acc = (did[i] == tok) ? 1 : 0;
        } else {
            __syncthreads();  // protect sh_acc/sh_tok against previous iteration's readers
            if (tid == 0) {
                const int td    = did[i];
                const float dat = dp[(size_t)i * V + td];
                const float tat = trow[td];
                sh_acc = (dat > 0.0f && tat >= up[i] * dat) ? 1 : 0;
                sh_tok = td;
            }
            __syncthreads();
            acc = sh_acc;
            tok = sh_tok;
            if (!acc) {
                // recovered token: argmax over max(t-d,0)/q[req]
                const float4* t4 = (const float4*)trow;
                const float4* d4 = (const float4*)(dp + (size_t)i * V);
                const float4* q4 = (const float4*)(q  + (size_t)b * V);
                float bv = -1.0f; int bi = 0;
                for (int j = tid; j < V4; j += T) {
                    float4 t = t4[j], d = d4[j], qq = q4[j];
                    const int base = j << 2;
                    float r;
                    r = fmaxf(t.x - d.x, 0.0f) / qq.x; if (r > bv) { bv = r; bi = base;     }
                    r = fmaxf(t.y - d.y, 0.0f) / qq.y; if (r > bv) { bv = r; bi = base + 1; }
                    r = fmaxf(t.z - d.z, 0.0f) / qq.z; if (r > bv) { bv = r; bi = base + 2; }
                    r = fmaxf(t.w - d.w, 0.0f) / qq.w; if (r > bv) { bv = r; bi = base + 3; }
                }
                for (int j = (V4 << 2) + tid; j < V; j += T) {
                    float r = fmaxf(trow[j] - dp[(size_t)i * V + j], 0.0f)
                              / q[(size_t)b * V + j];
                    if (r > bv) { bv = r; bi = j; }
                }
                tok = block_argmax(bv, bi, s_v, s_i);
            }
        }
        if (tid == 0) row[p] = tok;   // first rejected position still gets its token
        if (!acc) { allacc = false; ++p; break; }
    }
    // positions p..S are placeholders; bonus at `len` iff every draft token accepted
    if (tid == 0) {
        for (int r = p; r <= S; ++r) row[r] = PLACEHOLDER;
        if (allacc) row[len] = bonus[b];
    }
}

extern "C" void kernel_launch(void* const* d_in, const int* in_sizes, int n_in,
                              void* d_out, int out_size, void* d_ws, size_t ws_size,
                              hipStream_t stream) {
    const float* dp  = (const float*)d_in[0];           // draft_probs  [N,V]
    const float* tp  = (const float*)d_in[1];           // target_probs [N,V]
    const float* up  = (const float*)d_in[2];           // uniform_probs [N]
    const float* q   = (const float*)d_in[3];           // q [B,V]
    const int*   cu  = (const int*)d_in[4];             // cu_num_draft_tokens [B]
    const int*   did = (const int*)d_in[5];             // draft_token_ids [N]
    const int*   bon = (const int*)d_in[6];             // bonus_token_ids [B]
    const void*  grd = d_in[7];                         // is_greedy [B] (encoding detected on device)

    const int B = in_sizes[4];
    const int N = in_sizes[5];
    const int V = in_sizes[0] / N;
    const int S = out_size / B - 1;

    fused_kernel<<<B, T, 0, stream>>>(dp, tp, up, q, cu, did, bon, grd,
                                      (int*)d_out, B, V, S);
}